// Round 11
// baseline (126.403 us; speedup 1.0000x reference)
//
#include <hip/hip_runtime.h>

#define BT 256           // 4 waves per block
#define RSTRIDE 68       // strip/V row stride in bytes (17 words, odd -> 2-way banks)
#define WLDS (64 * RSTRIDE)   // 4352 B per wave; block 17408 B -> LDS never caps occupancy

// Compiler-only fence: orders LDS ops across phases (HW DS is in-order per wave).
#define MEMFENCE asm volatile("" ::: "memory")

typedef __attribute__((ext_vector_type(8))) short short8;
typedef __attribute__((ext_vector_type(4))) float f32x4;
typedef __attribute__((ext_vector_type(4))) unsigned int u32x4;
typedef _Float16 h2 __attribute__((ext_vector_type(2)));

__device__ inline unsigned cvtpkbf(float a, float b) {   // 2xf32 -> 2xbf16 (RNE)
    unsigned d;
    asm("v_cvt_pk_bf16_f32 %0, %1, %2" : "=v"(d) : "v"(a), "v"(b));
    return d;
}
__device__ inline unsigned pkrtz(float a, float b) {     // 2xf32 -> 2xf16 (RTZ)
    unsigned d;
    asm("v_cvt_pkrtz_f16_f32 %0, %1, %2" : "=v"(d) : "v"(a), "v"(b));
    return d;
}
__device__ inline unsigned pkfma(unsigned a, unsigned b, unsigned c) {
    unsigned d;
    asm("v_pk_fma_f16 %0, %1, %2, %3" : "=v"(d) : "v"(a), "v"(b), "v"(c));
    return d;
}
__device__ inline unsigned pkmax(unsigned a, unsigned b) {
    unsigned d;
    asm("v_pk_max_f16 %0, %1, %2" : "=v"(d) : "v"(a), "v"(b));
    return d;
}
__device__ inline unsigned pksub(unsigned a, unsigned b) {   // a - b
    unsigned d;
    asm("v_pk_add_f16 %0, %1, %2 neg_lo:[0,1] neg_hi:[0,1]" : "=v"(d) : "v"(a), "v"(b));
    return d;
}
__device__ inline unsigned pkneg(unsigned b) {               // -b
    unsigned d;
    asm("v_pk_add_f16 %0, 0, %1 neg_lo:[0,1] neg_hi:[0,1]" : "=v"(d) : "v"(b));
    return d;
}

// one VI step: D = step(S); pack (h,j): lo=V[h][j], hi=V[h][j+2]
__device__ inline void vistep(const unsigned (&S)[4][2], unsigned (&D)[4][2],
                              const unsigned (&pp)[4][2],
                              const unsigned (&aL)[4][2], const unsigned (&aR)[4][2],
                              const unsigned (&aU)[4][2], const unsigned (&aD)[4][2])
{
    unsigned shl[4], shr[4];
    #pragma unroll
    for (int h = 0; h < 4; ++h) {
        shl[h] = S[h][1] << 16;      // L-nb of (h,0): (bnd, V[h][1])
        shr[h] = S[h][0] >> 16;      // R-nb of (h,1): (V[h][2], bnd)
    }
    #pragma unroll
    for (int h = 0; h < 4; ++h)
        #pragma unroll
        for (int j = 0; j < 2; ++j) {
            unsigned vL = j ? S[h][0] : shl[h];
            unsigned vR = j ? shr[h] : S[h][1];
            unsigned tU = (h > 0) ? pkfma(pp[h][j], S[h-1][j], aU[h][j]) : aU[h][j];
            unsigned tD = (h < 3) ? pkfma(pp[h][j], S[h+1][j], aD[h][j]) : aD[h][j];
            unsigned m1 = pkmax(S[h][j], pkfma(pp[h][j], vL, aL[h][j]));
            unsigned m2 = pkmax(pkfma(pp[h][j], vR, aR[h][j]), tU);
            D[h][j] = pkmax(pkmax(m1, m2), tD);
        }
}

__global__ __launch_bounds__(BT, 5) void vin_kernel(
    const float* __restrict__ obs,
    const float* __restrict__ PhiW,
    const float* __restrict__ Phib,
    const float* __restrict__ LW,
    const float* __restrict__ Lb,
    float* __restrict__ out, int Btot)
{
    __shared__ __align__(16) char smem[4 * WLDS];   // 17408 B
    const int tid  = threadIdx.x;
    const int lane = tid & 63;
    const int wid  = tid >> 6;
    const int b    = blockIdx.x * BT + tid;
    // Btot % 64 == 0, waves entirely in or out; no barriers -> early return safe
    if (b >= Btot) return;

    char* wbase = smem + wid * WLDS;
    const int jn = lane & 15;
    const int g  = lane >> 4;
    const float* myobs = obs + (size_t)b * 48;
    const size_t wbsamp = (size_t)(blockIdx.x * BT + wid * 64);

    // ---- A-fragments DIRECT from global obs (L1/L2-hot; no LDS staging) ----
    // lane (g,jn) of tile m holds sample wbsamp+m*16+jn, elements 32t+8g..+7 as bf16
    short8 afrag[4][2];
    #pragma unroll
    for (int m = 0; m < 4; ++m) {
        const float* sr = obs + (wbsamp + m*16 + jn) * 48;
        float4 q0 = *reinterpret_cast<const float4*>(sr + 8*g);
        float4 q1 = *reinterpret_cast<const float4*>(sr + 8*g + 4);
        u32x4 t0;
        t0[0] = cvtpkbf(q0.x, q0.y); t0[1] = cvtpkbf(q0.z, q0.w);
        t0[2] = cvtpkbf(q1.x, q1.y); t0[3] = cvtpkbf(q1.z, q1.w);
        afrag[m][0] = __builtin_bit_cast(short8, t0);
        u32x4 tz = {0u, 0u, 0u, 0u};
        if (g < 2) {   // k = 32+8g..+7 valid only for g<2; k>=48 is zero pad
            float4 q2 = *reinterpret_cast<const float4*>(sr + 32 + 8*g);
            float4 q3 = *reinterpret_cast<const float4*>(sr + 36 + 8*g);
            tz[0] = cvtpkbf(q2.x, q2.y); tz[1] = cvtpkbf(q2.z, q2.w);
            tz[2] = cvtpkbf(q3.x, q3.y); tz[3] = cvtpkbf(q3.z, q3.w);
        }
        afrag[m][1] = __builtin_bit_cast(short8, tz);
    }

    // ---- agent index: channel 1 (els 3k+1) is exactly one-hot with value 1.0 ----
    float sidx = 0.0f;
    #pragma unroll
    for (int k = 1; k < 16; ++k)
        sidx = fmaf(myobs[3*k + 1], (float)k, sidx);
    const int idx = (int)(sidx + 0.5f);
    const int ai = idx >> 2;
    const int aj = idx & 3;

    // ---- sub_state gather (features 0..26) from ORIGINAL f32 obs (exact) ----
    float lg0 = Lb[0], lg1 = Lb[1], lg2 = Lb[2], lg3 = Lb[3];
    #pragma unroll
    for (int dh = 0; dh < 3; ++dh)
        #pragma unroll
        for (int dw = 0; dw < 3; ++dw) {
            int r = ai + dh - 1, c = aj + dw - 1;
            bool ok = ((unsigned)r < 4u) && ((unsigned)c < 4u);
            int ba = ok ? (r*4 + c) * 3 : 0;   // clamped addr, mask below
            float s0 = myobs[ba+0];
            float s1 = myobs[ba+1];
            float s2 = myobs[ba+2];
            if (!ok) { s0 = 0.f; s1 = 0.f; s2 = 0.f; }
            int f = (dh*3 + dw) * 3;
            lg0 = fmaf(s0, LW[0*36+f], fmaf(s1, LW[0*36+f+1], fmaf(s2, LW[0*36+f+2], lg0)));
            lg1 = fmaf(s0, LW[1*36+f], fmaf(s1, LW[1*36+f+1], fmaf(s2, LW[1*36+f+2], lg1)));
            lg2 = fmaf(s0, LW[2*36+f], fmaf(s1, LW[2*36+f+1], fmaf(s2, LW[2*36+f+2], lg2)));
            lg3 = fmaf(s0, LW[3*36+f], fmaf(s1, LW[3*36+f+1], fmaf(s2, LW[3*36+f+2], lg3)));
        }

    // ---- per column-tile: bfrag build + 8 MFMAs -> scatter -> readback ----
    float rinf[16], routf[16], pcf[16];
    const float bias[3] = {Phib[jn], Phib[16 + jn], Phib[32 + jn]};
    #pragma unroll
    for (int n = 0; n < 3; ++n) {
        // B-fragment for this tile (PhiW^T), built from global (L1-hot)
        short8 bf0, bf1;
        {
            const float* wrow = PhiW + (16*n + jn) * 48;
            float4 q0 = *reinterpret_cast<const float4*>(wrow + 8*g);
            float4 q1 = *reinterpret_cast<const float4*>(wrow + 8*g + 4);
            u32x4 t0;
            t0[0] = cvtpkbf(q0.x, q0.y); t0[1] = cvtpkbf(q0.z, q0.w);
            t0[2] = cvtpkbf(q1.x, q1.y); t0[3] = cvtpkbf(q1.z, q1.w);
            bf0 = __builtin_bit_cast(short8, t0);
            u32x4 tz = {0u, 0u, 0u, 0u};
            if (g < 2) {
                float4 q2 = *reinterpret_cast<const float4*>(wrow + 32 + 8*g);
                float4 q3 = *reinterpret_cast<const float4*>(wrow + 36 + 8*g);
                tz[0] = cvtpkbf(q2.x, q2.y); tz[1] = cvtpkbf(q2.z, q2.w);
                tz[2] = cvtpkbf(q3.x, q3.y); tz[3] = cvtpkbf(q3.z, q3.w);
            }
            bf1 = __builtin_bit_cast(short8, tz);
        }
        f32x4 acc[4];
        #pragma unroll
        for (int m = 0; m < 4; ++m) {
            float bn = bias[n];
            acc[m] = (f32x4){bn, bn, bn, bn};
            acc[m] = __builtin_amdgcn_mfma_f32_16x16x32_bf16(afrag[m][0], bf0, acc[m], 0, 0, 0);
            acc[m] = __builtin_amdgcn_mfma_f32_16x16x32_bf16(afrag[m][1], bf1, acc[m], 0, 0, 0);
        }
        // scatter D: lane holds col 16n+jn of rows m*16+g*4+r -> strip word jn
        #pragma unroll
        for (int m = 0; m < 4; ++m)
            #pragma unroll
            for (int r = 0; r < 4; ++r) {
                int row = m*16 + g*4 + r;
                *reinterpret_cast<float*>(wbase + row * RSTRIDE + jn * 4) = acc[m][r];
            }
        MEMFENCE;   // scatter before readback (RAW; in-order DS)
        // readback own row's 16 cols of this tile, route by col%3
        const char* myrow = wbase + lane * RSTRIDE;
        #pragma unroll
        for (int i = 0; i < 16; ++i) {
            float t = *reinterpret_cast<const float*>(myrow + i * 4);
            int c = 16*n + i;
            int cell = c / 3, ch = c - 3*cell;
            if (ch == 0)      rinf[cell]  = t;
            else if (ch == 1) routf[cell] = t;
            else              pcf[cell]   = t;
        }
        MEMFENCE;   // readback before next tile's scatter (WAR)
    }

    // ---- pack rin/rout/p into f16 pairs (cl, cl+2), build a* in packed math ----
    unsigned rinp[4][2], routp[4][2], pp[4][2];
    #pragma unroll
    for (int h = 0; h < 4; ++h)
        #pragma unroll
        for (int j = 0; j < 2; ++j) {
            int c0 = 4*h + j, c1 = 4*h + j + 2;
            rinp[h][j]  = pkrtz(rinf[c0], rinf[c1]);
            routp[h][j] = pkrtz(routf[c0], routf[c1]);
            pp[h][j]    = pkrtz(pcf[c0], pcf[c1]);
        }
    unsigned aL2[4][2], aR2[4][2], aU2[4][2], aD2[4][2];
    #pragma unroll
    for (int h = 0; h < 4; ++h) {
        aL2[h][0] = pksub(rinp[h][1] << 16, routp[h][0]);
        aL2[h][1] = pksub(rinp[h][0], routp[h][1]);
        aR2[h][0] = pksub(rinp[h][1], routp[h][0]);
        aR2[h][1] = pksub(rinp[h][0] >> 16, routp[h][1]);
        #pragma unroll
        for (int j = 0; j < 2; ++j) {
            aU2[h][j] = (h > 0) ? pksub(rinp[h-1][j], routp[h][j]) : pkneg(routp[0][j]);
            aD2[h][j] = (h < 3) ? pksub(rinp[h+1][j], routp[h][j]) : pkneg(routp[3][j]);
        }
    }

    // ---- K=20 VI steps, packed f16, unrolled x2 (ping-pong, no copies) ----
    unsigned Vp[4][2], Vn[4][2];
    #pragma unroll
    for (int h = 0; h < 4; ++h) { Vp[h][0] = 0u; Vp[h][1] = 0u; }
    #pragma unroll 1
    for (int s = 0; s < 10; ++s) {
        vistep(Vp, Vn, pp, aL2, aR2, aU2, aD2);
        vistep(Vn, Vp, pp, aL2, aR2, aU2, aD2);
    }

    // ---- V to own LDS row words 0..15 (+zero sentinel word 16), 3x3 gather ----
    {
        char* myrow = wbase + lane * RSTRIDE;
        #pragma unroll
        for (int h = 0; h < 4; ++h) {
            h2 a = __builtin_bit_cast(h2, Vp[h][0]);
            h2 c = __builtin_bit_cast(h2, Vp[h][1]);
            // cells 4h..4h+3 at words 4h..4h+3
            reinterpret_cast<float*>(myrow)[4*h+0] = (float)a[0];
            reinterpret_cast<float*>(myrow)[4*h+1] = (float)c[0];
            reinterpret_cast<float*>(myrow)[4*h+2] = (float)a[1];
            reinterpret_cast<float*>(myrow)[4*h+3] = (float)c[1];
        }
        reinterpret_cast<float*>(myrow)[16] = 0.0f;   // gather sentinel
    }
    MEMFENCE;   // V writes before V gather reads (RAW; in-order DS)
    {
        const float* myv = reinterpret_cast<const float*>(wbase + lane * RSTRIDE);
        #pragma unroll
        for (int dh = 0; dh < 3; ++dh)
            #pragma unroll
            for (int dw = 0; dw < 3; ++dw) {
                int r = ai + dh - 1, c = aj + dw - 1;
                bool ok = ((unsigned)r < 4u) && ((unsigned)c < 4u);
                int ba = ok ? (r*4 + c) : 16;   // 16 -> zero sentinel
                float v = myv[ba];
                int f = 27 + dh*3 + dw;
                lg0 = fmaf(v, LW[0*36+f], lg0);
                lg1 = fmaf(v, LW[1*36+f], lg1);
                lg2 = fmaf(v, LW[2*36+f], lg2);
                lg3 = fmaf(v, LW[3*36+f], lg3);
            }
    }

    reinterpret_cast<float4*>(out)[b] = make_float4(lg0, lg1, lg2, lg3);
}

extern "C" void kernel_launch(void* const* d_in, const int* in_sizes, int n_in,
                              void* d_out, int out_size, void* d_ws, size_t ws_size,
                              hipStream_t stream) {
    const float* obs  = (const float*)d_in[0];
    const float* PhiW = (const float*)d_in[1];
    const float* Phib = (const float*)d_in[2];
    const float* LW   = (const float*)d_in[3];
    const float* Lb   = (const float*)d_in[4];
    float* out = (float*)d_out;

    const int Btot = in_sizes[0] / 48;   // 1,000,000
    const int grid = (Btot + BT - 1) / BT;
    hipLaunchKernelGGL(vin_kernel, dim3(grid), dim3(BT), 0, stream,
                       obs, PhiW, Phib, LW, Lb, out, Btot);
}

// Round 12
// 113.297 us; speedup vs baseline: 1.1157x; 1.1157x over previous
//
#include <hip/hip_runtime.h>

#define BT 256           // 4 waves per block
#define ROWB 128         // LDS row stride: 32 words = 8 x 16B slots
#define WLDS (64 * ROWB) // 8192 B per wave -> 32768 B per block -> 5 blocks/CU
// A-row: 64 shorts = 48 bf16 obs + 16 zeros (K-pad + gather sentinel)
// strip (post-MFMA, per column-tile): logical words 0..15, reused 3x (overlays A)
// V-area (post-VI): logical words 0..15 + zero sentinel word 16
// All LDS accesses use XOR swizzle: byte = linear_byte ^ ((row&7)<<4)
//  -> own-row b128 ops and D-scatter are bank-conflict-free.

// Compiler-only fence: orders LDS ops across overlay phases (HW DS is in-order per wave).
#define MEMFENCE asm volatile("" ::: "memory")

typedef __attribute__((ext_vector_type(8))) short short8;
typedef __attribute__((ext_vector_type(4))) float f32x4;
typedef __attribute__((ext_vector_type(4))) unsigned int u32x4;
typedef _Float16 h2 __attribute__((ext_vector_type(2)));

__device__ inline unsigned cvtpkbf(float a, float b) {   // 2xf32 -> 2xbf16 (RNE)
    unsigned d;
    asm("v_cvt_pk_bf16_f32 %0, %1, %2" : "=v"(d) : "v"(a), "v"(b));
    return d;
}
__device__ inline float b2f(short s) {
    unsigned u = ((unsigned)(unsigned short)s) << 16;
    return __builtin_bit_cast(float, u);
}
__device__ inline unsigned pkrtz(float a, float b) {     // 2xf32 -> 2xf16 (RTZ)
    unsigned d;
    asm("v_cvt_pkrtz_f16_f32 %0, %1, %2" : "=v"(d) : "v"(a), "v"(b));
    return d;
}
__device__ inline unsigned pkfma(unsigned a, unsigned b, unsigned c) {
    unsigned d;
    asm("v_pk_fma_f16 %0, %1, %2, %3" : "=v"(d) : "v"(a), "v"(b), "v"(c));
    return d;
}
__device__ inline unsigned pkmax(unsigned a, unsigned b) {
    unsigned d;
    asm("v_pk_max_f16 %0, %1, %2" : "=v"(d) : "v"(a), "v"(b));
    return d;
}
__device__ inline unsigned pksub(unsigned a, unsigned b) {   // a - b
    unsigned d;
    asm("v_pk_add_f16 %0, %1, %2 neg_lo:[0,1] neg_hi:[0,1]" : "=v"(d) : "v"(a), "v"(b));
    return d;
}
__device__ inline unsigned pkneg(unsigned b) {               // -b
    unsigned d;
    asm("v_pk_add_f16 %0, 0, %1 neg_lo:[0,1] neg_hi:[0,1]" : "=v"(d) : "v"(b));
    return d;
}

// one VI step: D = step(S); pack (h,j): lo=V[h][j], hi=V[h][j+2]
__device__ inline void vistep(const unsigned (&S)[4][2], unsigned (&D)[4][2],
                              const unsigned (&pp)[4][2],
                              const unsigned (&aL)[4][2], const unsigned (&aR)[4][2],
                              const unsigned (&aU)[4][2], const unsigned (&aD)[4][2])
{
    unsigned shl[4], shr[4];
    #pragma unroll
    for (int h = 0; h < 4; ++h) {
        shl[h] = S[h][1] << 16;      // L-nb of (h,0): (bnd, V[h][1])
        shr[h] = S[h][0] >> 16;      // R-nb of (h,1): (V[h][2], bnd)
    }
    #pragma unroll
    for (int h = 0; h < 4; ++h)
        #pragma unroll
        for (int j = 0; j < 2; ++j) {
            unsigned vL = j ? S[h][0] : shl[h];
            unsigned vR = j ? shr[h] : S[h][1];
            unsigned tU = (h > 0) ? pkfma(pp[h][j], S[h-1][j], aU[h][j]) : aU[h][j];
            unsigned tD = (h < 3) ? pkfma(pp[h][j], S[h+1][j], aD[h][j]) : aD[h][j];
            unsigned m1 = pkmax(S[h][j], pkfma(pp[h][j], vL, aL[h][j]));
            unsigned m2 = pkmax(pkfma(pp[h][j], vR, aR[h][j]), tU);
            D[h][j] = pkmax(pkmax(m1, m2), tD);
        }
}

// one column-tile: bfrag build + 8 MFMAs -> swizzled scatter -> readback 16 f32
__device__ inline void tile_pass(int n, char* wbase, int jn, int g, int xb,
                                 const short8 (&afrag)[4][2],
                                 const float* __restrict__ PhiW, float bn,
                                 float (&rv)[16])
{
    // B-fragment (PhiW^T) from global, L1-hot
    short8 bf0, bf1;
    {
        const float* wrow = PhiW + (16*n + jn) * 48;
        float4 q0 = *reinterpret_cast<const float4*>(wrow + 8*g);
        float4 q1 = *reinterpret_cast<const float4*>(wrow + 8*g + 4);
        u32x4 t0;
        t0[0] = cvtpkbf(q0.x, q0.y); t0[1] = cvtpkbf(q0.z, q0.w);
        t0[2] = cvtpkbf(q1.x, q1.y); t0[3] = cvtpkbf(q1.z, q1.w);
        bf0 = __builtin_bit_cast(short8, t0);
        u32x4 tz = {0u, 0u, 0u, 0u};
        if (g < 2) {   // k = 32+8g..+7 valid only for g<2; k>=48 zero pad
            float4 q2 = *reinterpret_cast<const float4*>(wrow + 32 + 8*g);
            float4 q3 = *reinterpret_cast<const float4*>(wrow + 36 + 8*g);
            tz[0] = cvtpkbf(q2.x, q2.y); tz[1] = cvtpkbf(q2.z, q2.w);
            tz[2] = cvtpkbf(q3.x, q3.y); tz[3] = cvtpkbf(q3.z, q3.w);
        }
        bf1 = __builtin_bit_cast(short8, tz);
    }
    f32x4 acc[4];
    #pragma unroll
    for (int m = 0; m < 4; ++m) {
        acc[m] = (f32x4){bn, bn, bn, bn};
        acc[m] = __builtin_amdgcn_mfma_f32_16x16x32_bf16(afrag[m][0], bf0, acc[m], 0, 0, 0);
        acc[m] = __builtin_amdgcn_mfma_f32_16x16x32_bf16(afrag[m][1], bf1, acc[m], 0, 0, 0);
    }
    // scatter D: lane holds col 16n+jn of rows R=m*16+4g+r; word jn, swizzled.
    // Per instruction banks = 4*((jn>>2)^(R&7)) + (jn&3): conflict-free.
    #pragma unroll
    for (int m = 0; m < 4; ++m)
        #pragma unroll
        for (int r = 0; r < 4; ++r) {
            int R = m*16 + 4*g + r;
            int byte = R * ROWB + ((jn * 4) ^ (((4*g + r) & 7) << 4));
            *reinterpret_cast<float*>(wbase + byte) = acc[m][r];
        }
    MEMFENCE;   // scatter before readback (RAW; in-order DS)
    // readback own row's 16 cols of this tile (4 x b128, slot-contiguous)
    char* myrow = wbase + ((threadIdx.x & 63) * ROWB);
    #pragma unroll
    for (int s = 0; s < 4; ++s) {
        f32x4 t = *reinterpret_cast<const f32x4*>(myrow + ((s * 16) ^ xb));
        rv[4*s+0] = t[0]; rv[4*s+1] = t[1]; rv[4*s+2] = t[2]; rv[4*s+3] = t[3];
    }
    MEMFENCE;   // readback before next tile's scatter (WAR)
}

__global__ __launch_bounds__(BT, 5) void vin_kernel(
    const float* __restrict__ obs,
    const float* __restrict__ PhiW,
    const float* __restrict__ Phib,
    const float* __restrict__ LW,
    const float* __restrict__ Lb,
    float* __restrict__ out, int Btot)
{
    __shared__ __align__(16) char smem[4 * WLDS];   // 32768 B
    const int tid  = threadIdx.x;
    const int lane = tid & 63;
    const int wid  = tid >> 6;
    const int b    = blockIdx.x * BT + tid;
    // Btot % 64 == 0, waves entirely in or out; no barriers -> early return safe
    if (b >= Btot) return;

    char* wbase = smem + wid * WLDS;
    char* myrow = wbase + lane * ROWB;
    const int jn = lane & 15;
    const int g  = lane >> 4;
    const int xb = (lane & 7) << 4;   // own-row swizzle

    // ---- load obs row (12x float4, coalesced); cvt to packed bf16 + agent idx ----
    unsigned op[24];
    float sidx = 0.0f;
    {
        const float4* g4 = reinterpret_cast<const float4*>(obs + (size_t)b * 48);
        #pragma unroll
        for (int q = 0; q < 12; ++q) {
            float4 t = g4[q];
            float va[4] = {t.x, t.y, t.z, t.w};
            #pragma unroll
            for (int e = 0; e < 4; ++e) {
                int E = 4*q + e;
                if ((E % 3) == 1 && (E / 3) > 0)   // channel-1 one-hot, value 1.0
                    sidx = fmaf(va[e], (float)(E / 3), sidx);
            }
            op[2*q]   = cvtpkbf(va[0], va[1]);
            op[2*q+1] = cvtpkbf(va[2], va[3]);
        }
    }
    const int idx = (int)(sidx + 0.5f);
    const int ai = idx >> 2;
    const int aj = idx & 3;

    // ---- write own obs row to A-area (swizzled; 6 data + 2 zero slots) ----
    {
        #pragma unroll
        for (int q = 0; q < 6; ++q) {
            u32x4 v = { op[4*q], op[4*q+1], op[4*q+2], op[4*q+3] };
            *reinterpret_cast<u32x4*>(myrow + ((q * 16) ^ xb)) = v;
        }
        u32x4 z = {0u, 0u, 0u, 0u};
        *reinterpret_cast<u32x4*>(myrow + ((6 * 16) ^ xb)) = z;   // shorts 48..55
        *reinterpret_cast<u32x4*>(myrow + ((7 * 16) ^ xb)) = z;   // shorts 56..63
    }
    MEMFENCE;   // A-writes before gather reads (compiler order; HW in-order)

    // ---- sub_state gather (features 0..26); OOB -> zero-pad sentinel at short 48 ----
    float lg0 = Lb[0], lg1 = Lb[1], lg2 = Lb[2], lg3 = Lb[3];
    #pragma unroll
    for (int dh = 0; dh < 3; ++dh)
        #pragma unroll
        for (int dw = 0; dw < 3; ++dw) {
            int r = ai + dh - 1, c = aj + dw - 1;
            bool ok = ((unsigned)r < 4u) && ((unsigned)c < 4u);
            int ba = ok ? (r*4 + c) * 3 : 48;
            float s0 = b2f(*reinterpret_cast<const short*>(myrow + (((ba+0)*2) ^ xb)));
            float s1 = b2f(*reinterpret_cast<const short*>(myrow + (((ba+1)*2) ^ xb)));
            float s2 = b2f(*reinterpret_cast<const short*>(myrow + (((ba+2)*2) ^ xb)));
            int f = (dh*3 + dw) * 3;
            lg0 = fmaf(s0, LW[0*36+f], fmaf(s1, LW[0*36+f+1], fmaf(s2, LW[0*36+f+2], lg0)));
            lg1 = fmaf(s0, LW[1*36+f], fmaf(s1, LW[1*36+f+1], fmaf(s2, LW[1*36+f+2], lg1)));
            lg2 = fmaf(s0, LW[2*36+f], fmaf(s1, LW[2*36+f+1], fmaf(s2, LW[2*36+f+2], lg2)));
            lg3 = fmaf(s0, LW[3*36+f], fmaf(s1, LW[3*36+f+1], fmaf(s2, LW[3*36+f+2], lg3)));
        }

    // ---- A-fragments: lane reads row m*16+jn, slots g and 4+g (swizzled) ----
    // slots 6,7 are zeros -> frag1 for g>=2 reads zeros (K-pad), no branch.
    short8 afrag[4][2];
    #pragma unroll
    for (int m = 0; m < 4; ++m) {
        const char* rp = wbase + (m*16 + jn) * ROWB;
        const int xr = (jn & 7) << 4;
        afrag[m][0] = *reinterpret_cast<const short8*>(rp + ((16*g) ^ xr));
        afrag[m][1] = *reinterpret_cast<const short8*>(rp + ((64 + 16*g) ^ xr));
    }
    MEMFENCE;   // afrag reads before strip scatter overwrites A (WAR; in-order DS)

    // ---- 3 column-tiles with incremental f16 packing of rin/rout/p ----
    unsigned rinp[4][2], routp[4][2], pp[4][2];
    float rv[16];
    const float b0 = Phib[jn], b1 = Phib[16 + jn], b2 = Phib[32 + jn];

    tile_pass(0, wbase, jn, g, xb, afrag, PhiW, b0, rv);   // cols 0..15
    rinp[0][0] = pkrtz(rv[0], rv[6]);  routp[0][0] = pkrtz(rv[1], rv[7]);  pp[0][0] = pkrtz(rv[2], rv[8]);
    rinp[0][1] = pkrtz(rv[3], rv[9]);  routp[0][1] = pkrtz(rv[4], rv[10]); pp[0][1] = pkrtz(rv[5], rv[11]);
    float c4r = rv[12], c4o = rv[13], c4p = rv[14], c5r = rv[15];

    tile_pass(1, wbase, jn, g, xb, afrag, PhiW, b1, rv);   // cols 16..31
    {
        float c5o = rv[0], c5p = rv[1];
        rinp[1][0] = pkrtz(c4r, rv[2]); routp[1][0] = pkrtz(c4o, rv[3]); pp[1][0] = pkrtz(c4p, rv[4]);
        rinp[1][1] = pkrtz(c5r, rv[5]); routp[1][1] = pkrtz(c5o, rv[6]); pp[1][1] = pkrtz(c5p, rv[7]);
    }
    float c8r = rv[8],  c8o = rv[9],  c8p = rv[10];
    float c9r = rv[11], c9o = rv[12], c9p = rv[13];
    float c10r = rv[14], c10o = rv[15];

    tile_pass(2, wbase, jn, g, xb, afrag, PhiW, b2, rv);   // cols 32..47
    rinp[2][0] = pkrtz(c8r, c10r);     routp[2][0] = pkrtz(c8o, c10o);    pp[2][0] = pkrtz(c8p, rv[0]);
    rinp[2][1] = pkrtz(c9r, rv[1]);    routp[2][1] = pkrtz(c9o, rv[2]);   pp[2][1] = pkrtz(c9p, rv[3]);
    rinp[3][0] = pkrtz(rv[4], rv[10]); routp[3][0] = pkrtz(rv[5], rv[11]); pp[3][0] = pkrtz(rv[6], rv[12]);
    rinp[3][1] = pkrtz(rv[7], rv[13]); routp[3][1] = pkrtz(rv[8], rv[14]); pp[3][1] = pkrtz(rv[9], rv[15]);

    // ---- build per-direction a* = rin_neighbor - rout in packed f16 ----
    unsigned aL2[4][2], aR2[4][2], aU2[4][2], aD2[4][2];
    #pragma unroll
    for (int h = 0; h < 4; ++h) {
        aL2[h][0] = pksub(rinp[h][1] << 16, routp[h][0]);
        aL2[h][1] = pksub(rinp[h][0], routp[h][1]);
        aR2[h][0] = pksub(rinp[h][1], routp[h][0]);
        aR2[h][1] = pksub(rinp[h][0] >> 16, routp[h][1]);
        #pragma unroll
        for (int j = 0; j < 2; ++j) {
            aU2[h][j] = (h > 0) ? pksub(rinp[h-1][j], routp[h][j]) : pkneg(routp[0][j]);
            aD2[h][j] = (h < 3) ? pksub(rinp[h+1][j], routp[h][j]) : pkneg(routp[3][j]);
        }
    }

    // ---- K=20 VI steps, packed f16, unrolled x2 (ping-pong) ----
    unsigned Vp[4][2], Vn[4][2];
    #pragma unroll
    for (int h = 0; h < 4; ++h) { Vp[h][0] = 0u; Vp[h][1] = 0u; }
    #pragma unroll 1
    for (int s = 0; s < 10; ++s) {
        vistep(Vp, Vn, pp, aL2, aR2, aU2, aD2);
        vistep(Vn, Vp, pp, aL2, aR2, aU2, aD2);
    }

    // ---- V to own row words 0..15 (+zero sentinel word 16), swizzled ----
    {
        #pragma unroll
        for (int h = 0; h < 4; ++h) {
            h2 a = __builtin_bit_cast(h2, Vp[h][0]);
            h2 c = __builtin_bit_cast(h2, Vp[h][1]);
            *reinterpret_cast<f32x4*>(myrow + ((h * 16) ^ xb)) =
                (f32x4){(float)a[0], (float)c[0], (float)a[1], (float)c[1]};
        }
        *reinterpret_cast<float*>(myrow + (64 ^ xb)) = 0.0f;   // word 16 sentinel
    }
    MEMFENCE;   // V writes before V gather reads (RAW; in-order DS)
    #pragma unroll
    for (int dh = 0; dh < 3; ++dh)
        #pragma unroll
        for (int dw = 0; dw < 3; ++dw) {
            int r = ai + dh - 1, c = aj + dw - 1;
            bool ok = ((unsigned)r < 4u) && ((unsigned)c < 4u);
            int ba = ok ? (r*4 + c) : 16;   // 16 -> zero sentinel
            float v = *reinterpret_cast<const float*>(myrow + ((ba * 4) ^ xb));
            int f = 27 + dh*3 + dw;
            lg0 = fmaf(v, LW[0*36+f], lg0);
            lg1 = fmaf(v, LW[1*36+f], lg1);
            lg2 = fmaf(v, LW[2*36+f], lg2);
            lg3 = fmaf(v, LW[3*36+f], lg3);
        }

    reinterpret_cast<float4*>(out)[b] = make_float4(lg0, lg1, lg2, lg3);
}

extern "C" void kernel_launch(void* const* d_in, const int* in_sizes, int n_in,
                              void* d_out, int out_size, void* d_ws, size_t ws_size,
                              hipStream_t stream) {
    const float* obs  = (const float*)d_in[0];
    const float* PhiW = (const float*)d_in[1];
    const float* Phib = (const float*)d_in[2];
    const float* LW   = (const float*)d_in[3];
    const float* Lb   = (const float*)d_in[4];
    float* out = (float*)d_out;

    const int Btot = in_sizes[0] / 48;   // 1,000,000
    const int grid = (Btot + BT - 1) / BT;
    hipLaunchKernelGGL(vin_kernel, dim3(grid), dim3(BT), 0, stream,
                       obs, PhiW, Phib, LW, Lb, out, Btot);
}

// Round 13
// 67.740 us; speedup vs baseline: 1.8660x; 1.6725x over previous
//
#include <hip/hip_runtime.h>

#define BT 256           // 4 waves per block
#define ROWB 128         // LDS row stride: 32 words = 8 x 16B slots
#define WLDS (64 * ROWB) // 8192 B per wave -> 32768 B per block
// A-row: 64 shorts = 48 bf16 obs + 16 zeros (K-pad + gather sentinel)
// strip (post-MFMA, per column-tile): logical words 0..15, reused 3x (overlays A)
// V-area (post-VI): logical words 0..15 + zero sentinel word 16
// All LDS accesses use XOR swizzle: byte = linear_byte ^ ((row&7)<<4)

// Compiler-only fence: orders LDS ops across overlay phases (HW DS is in-order per wave).
#define MEMFENCE asm volatile("" ::: "memory")

typedef __attribute__((ext_vector_type(8))) short short8;
typedef __attribute__((ext_vector_type(4))) float f32x4;
typedef __attribute__((ext_vector_type(4))) unsigned int u32x4;
typedef _Float16 h2 __attribute__((ext_vector_type(2)));

__device__ inline unsigned cvtpkbf(float a, float b) {   // 2xf32 -> 2xbf16 (RNE)
    unsigned d;
    asm("v_cvt_pk_bf16_f32 %0, %1, %2" : "=v"(d) : "v"(a), "v"(b));
    return d;
}
__device__ inline float b2f(short s) {
    unsigned u = ((unsigned)(unsigned short)s) << 16;
    return __builtin_bit_cast(float, u);
}
__device__ inline unsigned pkrtz(float a, float b) {     // 2xf32 -> 2xf16 (RTZ)
    unsigned d;
    asm("v_cvt_pkrtz_f16_f32 %0, %1, %2" : "=v"(d) : "v"(a), "v"(b));
    return d;
}
__device__ inline unsigned pkfma(unsigned a, unsigned b, unsigned c) {
    unsigned d;
    asm("v_pk_fma_f16 %0, %1, %2, %3" : "=v"(d) : "v"(a), "v"(b), "v"(c));
    return d;
}
__device__ inline unsigned pkmax(unsigned a, unsigned b) {
    unsigned d;
    asm("v_pk_max_f16 %0, %1, %2" : "=v"(d) : "v"(a), "v"(b));
    return d;
}
__device__ inline unsigned pksub(unsigned a, unsigned b) {   // a - b
    unsigned d;
    asm("v_pk_add_f16 %0, %1, %2 neg_lo:[0,1] neg_hi:[0,1]" : "=v"(d) : "v"(a), "v"(b));
    return d;
}
__device__ inline unsigned pkneg(unsigned b) {               // -b
    unsigned d;
    asm("v_pk_add_f16 %0, 0, %1 neg_lo:[0,1] neg_hi:[0,1]" : "=v"(d) : "v"(b));
    return d;
}

// one VI step: D = step(S); pack (h,j): lo=V[h][j], hi=V[h][j+2]
__device__ inline void vistep(const unsigned (&S)[4][2], unsigned (&D)[4][2],
                              const unsigned (&pp)[4][2],
                              const unsigned (&aL)[4][2], const unsigned (&aR)[4][2],
                              const unsigned (&aU)[4][2], const unsigned (&aD)[4][2])
{
    unsigned shl[4], shr[4];
    #pragma unroll
    for (int h = 0; h < 4; ++h) {
        shl[h] = S[h][1] << 16;      // L-nb of (h,0): (bnd, V[h][1])
        shr[h] = S[h][0] >> 16;      // R-nb of (h,1): (V[h][2], bnd)
    }
    #pragma unroll
    for (int h = 0; h < 4; ++h)
        #pragma unroll
        for (int j = 0; j < 2; ++j) {
            unsigned vL = j ? S[h][0] : shl[h];
            unsigned vR = j ? shr[h] : S[h][1];
            unsigned tU = (h > 0) ? pkfma(pp[h][j], S[h-1][j], aU[h][j]) : aU[h][j];
            unsigned tD = (h < 3) ? pkfma(pp[h][j], S[h+1][j], aD[h][j]) : aD[h][j];
            unsigned m1 = pkmax(S[h][j], pkfma(pp[h][j], vL, aL[h][j]));
            unsigned m2 = pkmax(pkfma(pp[h][j], vR, aR[h][j]), tU);
            D[h][j] = pkmax(pkmax(m1, m2), tD);
        }
}

// one column-tile: bfrag build + 8 MFMAs -> swizzled scatter -> readback 16 f32
__device__ inline void tile_pass(int n, char* wbase, int jn, int g, int xb,
                                 const short8 (&afrag)[4][2],
                                 const float* __restrict__ PhiW, float bn,
                                 float (&rv)[16])
{
    // B-fragment (PhiW^T) from global, L1-hot
    short8 bf0, bf1;
    {
        const float* wrow = PhiW + (16*n + jn) * 48;
        float4 q0 = *reinterpret_cast<const float4*>(wrow + 8*g);
        float4 q1 = *reinterpret_cast<const float4*>(wrow + 8*g + 4);
        u32x4 t0;
        t0[0] = cvtpkbf(q0.x, q0.y); t0[1] = cvtpkbf(q0.z, q0.w);
        t0[2] = cvtpkbf(q1.x, q1.y); t0[3] = cvtpkbf(q1.z, q1.w);
        bf0 = __builtin_bit_cast(short8, t0);
        u32x4 tz = {0u, 0u, 0u, 0u};
        if (g < 2) {   // k = 32+8g..+7 valid only for g<2; k>=48 zero pad
            float4 q2 = *reinterpret_cast<const float4*>(wrow + 32 + 8*g);
            float4 q3 = *reinterpret_cast<const float4*>(wrow + 36 + 8*g);
            tz[0] = cvtpkbf(q2.x, q2.y); tz[1] = cvtpkbf(q2.z, q2.w);
            tz[2] = cvtpkbf(q3.x, q3.y); tz[3] = cvtpkbf(q3.z, q3.w);
        }
        bf1 = __builtin_bit_cast(short8, tz);
    }
    f32x4 acc[4];
    #pragma unroll
    for (int m = 0; m < 4; ++m) {
        acc[m] = (f32x4){bn, bn, bn, bn};
        acc[m] = __builtin_amdgcn_mfma_f32_16x16x32_bf16(afrag[m][0], bf0, acc[m], 0, 0, 0);
        acc[m] = __builtin_amdgcn_mfma_f32_16x16x32_bf16(afrag[m][1], bf1, acc[m], 0, 0, 0);
    }
    // scatter D: lane holds col 16n+jn of rows R=m*16+4g+r; word jn, swizzled.
    // Per instruction banks = jn ^ 4*((4g+r)&7): 2 lanes/bank -> free.
    #pragma unroll
    for (int m = 0; m < 4; ++m)
        #pragma unroll
        for (int r = 0; r < 4; ++r) {
            int R = m*16 + 4*g + r;
            int byte = R * ROWB + ((jn * 4) ^ (((4*g + r) & 7) << 4));
            *reinterpret_cast<float*>(wbase + byte) = acc[m][r];
        }
    MEMFENCE;   // scatter before readback (RAW; in-order DS)
    // readback own row's 16 cols of this tile (4 x b128, slot-contiguous)
    char* myrow = wbase + ((threadIdx.x & 63) * ROWB);
    #pragma unroll
    for (int s = 0; s < 4; ++s) {
        f32x4 t = *reinterpret_cast<const f32x4*>(myrow + ((s * 16) ^ xb));
        rv[4*s+0] = t[0]; rv[4*s+1] = t[1]; rv[4*s+2] = t[2]; rv[4*s+3] = t[3];
    }
    MEMFENCE;   // readback before next tile's scatter (WAR)
}

__global__ __launch_bounds__(BT, 4) void vin_kernel(
    const float* __restrict__ obs,
    const float* __restrict__ PhiW,
    const float* __restrict__ Phib,
    const float* __restrict__ LW,
    const float* __restrict__ Lb,
    float* __restrict__ out, int Btot)
{
    __shared__ __align__(16) char smem[4 * WLDS];   // 32768 B
    const int tid  = threadIdx.x;
    const int lane = tid & 63;
    const int wid  = tid >> 6;
    const int b    = blockIdx.x * BT + tid;
    // Btot % 64 == 0, waves entirely in or out; no barriers -> early return safe
    if (b >= Btot) return;

    char* wbase = smem + wid * WLDS;
    char* myrow = wbase + lane * ROWB;
    const int jn = lane & 15;
    const int g  = lane >> 4;
    const int xb = (lane & 7) << 4;   // own-row swizzle

    // ---- load obs row (12x float4, coalesced); cvt to packed bf16 + agent idx ----
    unsigned op[24];
    float sidx = 0.0f;
    {
        const float4* g4 = reinterpret_cast<const float4*>(obs + (size_t)b * 48);
        #pragma unroll
        for (int q = 0; q < 12; ++q) {
            float4 t = g4[q];
            float va[4] = {t.x, t.y, t.z, t.w};
            #pragma unroll
            for (int e = 0; e < 4; ++e) {
                int E = 4*q + e;
                if ((E % 3) == 1 && (E / 3) > 0)   // channel-1 one-hot, value 1.0
                    sidx = fmaf(va[e], (float)(E / 3), sidx);
            }
            op[2*q]   = cvtpkbf(va[0], va[1]);
            op[2*q+1] = cvtpkbf(va[2], va[3]);
        }
    }
    const int idx = (int)(sidx + 0.5f);
    const int ai = idx >> 2;
    const int aj = idx & 3;

    // ---- write own obs row to A-area (swizzled; 6 data + 2 zero slots) ----
    {
        #pragma unroll
        for (int q = 0; q < 6; ++q) {
            u32x4 v = { op[4*q], op[4*q+1], op[4*q+2], op[4*q+3] };
            *reinterpret_cast<u32x4*>(myrow + ((q * 16) ^ xb)) = v;
        }
        u32x4 z = {0u, 0u, 0u, 0u};
        *reinterpret_cast<u32x4*>(myrow + ((6 * 16) ^ xb)) = z;   // shorts 48..55
        *reinterpret_cast<u32x4*>(myrow + ((7 * 16) ^ xb)) = z;   // shorts 56..63
    }
    MEMFENCE;   // A-writes before gather reads (compiler order; HW in-order)

    // ---- sub_state gather (features 0..26); OOB -> zero-pad sentinel at short 48 ----
    float lg0 = Lb[0], lg1 = Lb[1], lg2 = Lb[2], lg3 = Lb[3];
    #pragma unroll
    for (int dh = 0; dh < 3; ++dh)
        #pragma unroll
        for (int dw = 0; dw < 3; ++dw) {
            int r = ai + dh - 1, c = aj + dw - 1;
            bool ok = ((unsigned)r < 4u) && ((unsigned)c < 4u);
            int ba = ok ? (r*4 + c) * 3 : 48;
            float s0 = b2f(*reinterpret_cast<const short*>(myrow + (((ba+0)*2) ^ xb)));
            float s1 = b2f(*reinterpret_cast<const short*>(myrow + (((ba+1)*2) ^ xb)));
            float s2 = b2f(*reinterpret_cast<const short*>(myrow + (((ba+2)*2) ^ xb)));
            int f = (dh*3 + dw) * 3;
            lg0 = fmaf(s0, LW[0*36+f], fmaf(s1, LW[0*36+f+1], fmaf(s2, LW[0*36+f+2], lg0)));
            lg1 = fmaf(s0, LW[1*36+f], fmaf(s1, LW[1*36+f+1], fmaf(s2, LW[1*36+f+2], lg1)));
            lg2 = fmaf(s0, LW[2*36+f], fmaf(s1, LW[2*36+f+1], fmaf(s2, LW[2*36+f+2], lg2)));
            lg3 = fmaf(s0, LW[3*36+f], fmaf(s1, LW[3*36+f+1], fmaf(s2, LW[3*36+f+2], lg3)));
        }

    // ---- A-fragments: lane reads row m*16+jn, slots g and 4+g (swizzled) ----
    // slots 6,7 are zeros -> frag1 for g>=2 reads zeros (K-pad), no branch.
    short8 afrag[4][2];
    #pragma unroll
    for (int m = 0; m < 4; ++m) {
        const char* rp = wbase + (m*16 + jn) * ROWB;
        const int xr = (jn & 7) << 4;
        afrag[m][0] = *reinterpret_cast<const short8*>(rp + ((16*g) ^ xr));
        afrag[m][1] = *reinterpret_cast<const short8*>(rp + ((64 + 16*g) ^ xr));
    }
    MEMFENCE;   // afrag reads before strip scatter overwrites A (WAR; in-order DS)

    // ---- 3 column-tiles with incremental f16 packing of rin/rout/p ----
    unsigned rinp[4][2], routp[4][2], pp[4][2];
    float rv[16];
    const float b0 = Phib[jn], b1 = Phib[16 + jn], b2 = Phib[32 + jn];

    tile_pass(0, wbase, jn, g, xb, afrag, PhiW, b0, rv);   // cols 0..15
    rinp[0][0] = pkrtz(rv[0], rv[6]);  routp[0][0] = pkrtz(rv[1], rv[7]);  pp[0][0] = pkrtz(rv[2], rv[8]);
    rinp[0][1] = pkrtz(rv[3], rv[9]);  routp[0][1] = pkrtz(rv[4], rv[10]); pp[0][1] = pkrtz(rv[5], rv[11]);
    float c4r = rv[12], c4o = rv[13], c4p = rv[14], c5r = rv[15];

    tile_pass(1, wbase, jn, g, xb, afrag, PhiW, b1, rv);   // cols 16..31
    {
        float c5o = rv[0], c5p = rv[1];
        rinp[1][0] = pkrtz(c4r, rv[2]); routp[1][0] = pkrtz(c4o, rv[3]); pp[1][0] = pkrtz(c4p, rv[4]);
        rinp[1][1] = pkrtz(c5r, rv[5]); routp[1][1] = pkrtz(c5o, rv[6]); pp[1][1] = pkrtz(c5p, rv[7]);
    }
    float c8r = rv[8],  c8o = rv[9],  c8p = rv[10];
    float c9r = rv[11], c9o = rv[12], c9p = rv[13];
    float c10r = rv[14], c10o = rv[15];

    tile_pass(2, wbase, jn, g, xb, afrag, PhiW, b2, rv);   // cols 32..47
    rinp[2][0] = pkrtz(c8r, c10r);     routp[2][0] = pkrtz(c8o, c10o);    pp[2][0] = pkrtz(c8p, rv[0]);
    rinp[2][1] = pkrtz(c9r, rv[1]);    routp[2][1] = pkrtz(c9o, rv[2]);   pp[2][1] = pkrtz(c9p, rv[3]);
    rinp[3][0] = pkrtz(rv[4], rv[10]); routp[3][0] = pkrtz(rv[5], rv[11]); pp[3][0] = pkrtz(rv[6], rv[12]);
    rinp[3][1] = pkrtz(rv[7], rv[13]); routp[3][1] = pkrtz(rv[8], rv[14]); pp[3][1] = pkrtz(rv[9], rv[15]);

    // ---- build per-direction a* = rin_neighbor - rout in packed f16 ----
    unsigned aL2[4][2], aR2[4][2], aU2[4][2], aD2[4][2];
    #pragma unroll
    for (int h = 0; h < 4; ++h) {
        aL2[h][0] = pksub(rinp[h][1] << 16, routp[h][0]);
        aL2[h][1] = pksub(rinp[h][0], routp[h][1]);
        aR2[h][0] = pksub(rinp[h][1], routp[h][0]);
        aR2[h][1] = pksub(rinp[h][0] >> 16, routp[h][1]);
        #pragma unroll
        for (int j = 0; j < 2; ++j) {
            aU2[h][j] = (h > 0) ? pksub(rinp[h-1][j], routp[h][j]) : pkneg(routp[0][j]);
            aD2[h][j] = (h < 3) ? pksub(rinp[h+1][j], routp[h][j]) : pkneg(routp[3][j]);
        }
    }

    // ---- K=20 VI steps, packed f16, unrolled x2 (ping-pong) ----
    unsigned Vp[4][2], Vn[4][2];
    #pragma unroll
    for (int h = 0; h < 4; ++h) { Vp[h][0] = 0u; Vp[h][1] = 0u; }
    #pragma unroll 1
    for (int s = 0; s < 10; ++s) {
        vistep(Vp, Vn, pp, aL2, aR2, aU2, aD2);
        vistep(Vn, Vp, pp, aL2, aR2, aU2, aD2);
    }

    // ---- V to own row words 0..15 (+zero sentinel word 16), swizzled ----
    {
        #pragma unroll
        for (int h = 0; h < 4; ++h) {
            h2 a = __builtin_bit_cast(h2, Vp[h][0]);
            h2 c = __builtin_bit_cast(h2, Vp[h][1]);
            *reinterpret_cast<f32x4*>(myrow + ((h * 16) ^ xb)) =
                (f32x4){(float)a[0], (float)c[0], (float)a[1], (float)c[1]};
        }
        *reinterpret_cast<float*>(myrow + (64 ^ xb)) = 0.0f;   // word 16 sentinel
    }
    MEMFENCE;   // V writes before V gather reads (RAW; in-order DS)
    #pragma unroll
    for (int dh = 0; dh < 3; ++dh)
        #pragma unroll
        for (int dw = 0; dw < 3; ++dw) {
            int r = ai + dh - 1, c = aj + dw - 1;
            bool ok = ((unsigned)r < 4u) && ((unsigned)c < 4u);
            int ba = ok ? (r*4 + c) : 16;   // 16 -> zero sentinel
            float v = *reinterpret_cast<const float*>(myrow + ((ba * 4) ^ xb));
            int f = 27 + dh*3 + dw;
            lg0 = fmaf(v, LW[0*36+f], lg0);
            lg1 = fmaf(v, LW[1*36+f], lg1);
            lg2 = fmaf(v, LW[2*36+f], lg2);
            lg3 = fmaf(v, LW[3*36+f], lg3);
        }

    reinterpret_cast<float4*>(out)[b] = make_float4(lg0, lg1, lg2, lg3);
}

extern "C" void kernel_launch(void* const* d_in, const int* in_sizes, int n_in,
                              void* d_out, int out_size, void* d_ws, size_t ws_size,
                              hipStream_t stream) {
    const float* obs  = (const float*)d_in[0];
    const float* PhiW = (const float*)d_in[1];
    const float* Phib = (const float*)d_in[2];
    const float* LW   = (const float*)d_in[3];
    const float* Lb   = (const float*)d_in[4];
    float* out = (float*)d_out;

    const int Btot = in_sizes[0] / 48;   // 1,000,000
    const int grid = (Btot + BT - 1) / BT;
    hipLaunchKernelGGL(vin_kernel, dim3(grid), dim3(BT), 0, stream,
                       obs, PhiW, Phib, LW, Lb, out, Btot);
}

// Round 14
// 64.087 us; speedup vs baseline: 1.9724x; 1.0570x over previous
//
#include <hip/hip_runtime.h>

#define BT 256           // 4 waves per block
#define ROWB 128         // LDS row stride: 32 words = 8 x 16B slots
#define WLDS (64 * ROWB) // 8192 B per wave -> 32768 B per block
// A-row: 64 shorts = 48 bf16 obs + 16 zeros (K-pad + gather sentinel)
// strip (post-MFMA, per column-tile): logical words 0..15, reused 3x (overlays A)
// V-area (post-VI): logical words 0..15 + zero sentinel word 16
// All LDS accesses use XOR swizzle: byte = linear_byte ^ ((row&7)<<4)

// Compiler-only fence: orders LDS ops across overlay phases (HW DS is in-order per wave).
#define MEMFENCE asm volatile("" ::: "memory")

typedef __attribute__((ext_vector_type(8))) short short8;
typedef __attribute__((ext_vector_type(4))) float f32x4;
typedef __attribute__((ext_vector_type(4))) unsigned int u32x4;
typedef _Float16 h2 __attribute__((ext_vector_type(2)));

__device__ inline unsigned cvtpkbf(float a, float b) {   // 2xf32 -> 2xbf16 (RNE)
    unsigned d;
    asm("v_cvt_pk_bf16_f32 %0, %1, %2" : "=v"(d) : "v"(a), "v"(b));
    return d;
}
__device__ inline float b2f(short s) {
    unsigned u = ((unsigned)(unsigned short)s) << 16;
    return __builtin_bit_cast(float, u);
}
__device__ inline unsigned pkrtz(float a, float b) {     // 2xf32 -> 2xf16 (RTZ)
    unsigned d;
    asm("v_cvt_pkrtz_f16_f32 %0, %1, %2" : "=v"(d) : "v"(a), "v"(b));
    return d;
}
__device__ inline unsigned pkfma(unsigned a, unsigned b, unsigned c) {
    unsigned d;
    asm("v_pk_fma_f16 %0, %1, %2, %3" : "=v"(d) : "v"(a), "v"(b), "v"(c));
    return d;
}
// fma with src1 halves SWAPPED: result.lo = a.lo*b.hi + c.lo ; result.hi = a.hi*b.lo + c.hi
__device__ inline unsigned pkfma_swap1(unsigned a, unsigned b, unsigned c) {
    unsigned d;
    asm("v_pk_fma_f16 %0, %1, %2, %3 op_sel:[0,1,0] op_sel_hi:[1,0,1]"
        : "=v"(d) : "v"(a), "v"(b), "v"(c));
    return d;
}
__device__ inline unsigned pkmax(unsigned a, unsigned b) {
    unsigned d;
    asm("v_pk_max_f16 %0, %1, %2" : "=v"(d) : "v"(a), "v"(b));
    return d;
}
__device__ inline unsigned pksub(unsigned a, unsigned b) {   // a - b
    unsigned d;
    asm("v_pk_add_f16 %0, %1, %2 neg_lo:[0,1] neg_hi:[0,1]" : "=v"(d) : "v"(a), "v"(b));
    return d;
}
__device__ inline unsigned pkneg(unsigned b) {               // -b
    unsigned d;
    asm("v_pk_add_f16 %0, 0, %1 neg_lo:[0,1] neg_hi:[0,1]" : "=v"(d) : "v"(b));
    return d;
}

// one VI step: D = step(S); pack (h,j): lo=V[h][j], hi=V[h][j+2]
// Boundary halves handled by half-masked p (pLm: lo=0, pRm: hi=0) + op_sel swap:
//  cL(h,0): lo = 0*X + aL.lo (exact boundary), hi = p.hi*V[h][1].lo + aL.hi
//  cR(h,1): lo = p.lo*V[h][0].hi + aR.lo,      hi = 0*X + aR.hi (boundary)
__device__ inline void vistep(const unsigned (&S)[4][2], unsigned (&D)[4][2],
                              const unsigned (&pp)[4][2],
                              const unsigned (&pLm)[4], const unsigned (&pRm)[4],
                              const unsigned (&aL)[4][2], const unsigned (&aR)[4][2],
                              const unsigned (&aU)[4][2], const unsigned (&aD)[4][2])
{
    #pragma unroll
    for (int h = 0; h < 4; ++h) {
        // j = 0 pack
        {
            unsigned cL = pkfma_swap1(pLm[h], S[h][1], aL[h][0]);
            unsigned cR = pkfma(pp[h][0], S[h][1], aR[h][0]);
            unsigned tU = (h > 0) ? pkfma(pp[h][0], S[h-1][0], aU[h][0]) : aU[h][0];
            unsigned tD = (h < 3) ? pkfma(pp[h][0], S[h+1][0], aD[h][0]) : aD[h][0];
            unsigned m1 = pkmax(S[h][0], cL);
            unsigned m2 = pkmax(cR, tU);
            D[h][0] = pkmax(pkmax(m1, m2), tD);
        }
        // j = 1 pack
        {
            unsigned cL = pkfma(pp[h][1], S[h][0], aL[h][1]);
            unsigned cR = pkfma_swap1(pRm[h], S[h][0], aR[h][1]);
            unsigned tU = (h > 0) ? pkfma(pp[h][1], S[h-1][1], aU[h][1]) : aU[h][1];
            unsigned tD = (h < 3) ? pkfma(pp[h][1], S[h+1][1], aD[h][1]) : aD[h][1];
            unsigned m1 = pkmax(S[h][1], cL);
            unsigned m2 = pkmax(cR, tU);
            D[h][1] = pkmax(pkmax(m1, m2), tD);
        }
    }
}

// one column-tile: bfrag build + 8 MFMAs -> swizzled scatter -> readback 16 f32
__device__ inline void tile_pass(int n, char* wbase, int jn, int g, int xb,
                                 const short8 (&afrag)[4][2],
                                 const float* __restrict__ PhiW, float bn,
                                 float (&rv)[16])
{
    // B-fragment (PhiW^T) from global, L1-hot
    short8 bf0, bf1;
    {
        const float* wrow = PhiW + (16*n + jn) * 48;
        float4 q0 = *reinterpret_cast<const float4*>(wrow + 8*g);
        float4 q1 = *reinterpret_cast<const float4*>(wrow + 8*g + 4);
        u32x4 t0;
        t0[0] = cvtpkbf(q0.x, q0.y); t0[1] = cvtpkbf(q0.z, q0.w);
        t0[2] = cvtpkbf(q1.x, q1.y); t0[3] = cvtpkbf(q1.z, q1.w);
        bf0 = __builtin_bit_cast(short8, t0);
        u32x4 tz = {0u, 0u, 0u, 0u};
        if (g < 2) {   // k = 32+8g..+7 valid only for g<2; k>=48 zero pad
            float4 q2 = *reinterpret_cast<const float4*>(wrow + 32 + 8*g);
            float4 q3 = *reinterpret_cast<const float4*>(wrow + 36 + 8*g);
            tz[0] = cvtpkbf(q2.x, q2.y); tz[1] = cvtpkbf(q2.z, q2.w);
            tz[2] = cvtpkbf(q3.x, q3.y); tz[3] = cvtpkbf(q3.z, q3.w);
        }
        bf1 = __builtin_bit_cast(short8, tz);
    }
    f32x4 acc[4];
    #pragma unroll
    for (int m = 0; m < 4; ++m) {
        acc[m] = (f32x4){bn, bn, bn, bn};
        acc[m] = __builtin_amdgcn_mfma_f32_16x16x32_bf16(afrag[m][0], bf0, acc[m], 0, 0, 0);
        acc[m] = __builtin_amdgcn_mfma_f32_16x16x32_bf16(afrag[m][1], bf1, acc[m], 0, 0, 0);
    }
    // scatter D: lane holds col 16n+jn of rows R=m*16+4g+r; word jn, swizzled.
    #pragma unroll
    for (int m = 0; m < 4; ++m)
        #pragma unroll
        for (int r = 0; r < 4; ++r) {
            int R = m*16 + 4*g + r;
            int byte = R * ROWB + ((jn * 4) ^ (((4*g + r) & 7) << 4));
            *reinterpret_cast<float*>(wbase + byte) = acc[m][r];
        }
    MEMFENCE;   // scatter before readback (RAW; in-order DS)
    // readback own row's 16 cols of this tile (4 x b128, slot-contiguous)
    char* myrow = wbase + ((threadIdx.x & 63) * ROWB);
    #pragma unroll
    for (int s = 0; s < 4; ++s) {
        f32x4 t = *reinterpret_cast<const f32x4*>(myrow + ((s * 16) ^ xb));
        rv[4*s+0] = t[0]; rv[4*s+1] = t[1]; rv[4*s+2] = t[2]; rv[4*s+3] = t[3];
    }
    MEMFENCE;   // readback before next tile's scatter (WAR)
}

__global__ __launch_bounds__(BT, 4) void vin_kernel(
    const float* __restrict__ obs,
    const float* __restrict__ PhiW,
    const float* __restrict__ Phib,
    const float* __restrict__ LW,
    const float* __restrict__ Lb,
    float* __restrict__ out, int Btot)
{
    __shared__ __align__(16) char smem[4 * WLDS];   // 32768 B
    const int tid  = threadIdx.x;
    const int lane = tid & 63;
    const int wid  = tid >> 6;
    const int b    = blockIdx.x * BT + tid;
    // Btot % 64 == 0, waves entirely in or out; no barriers -> early return safe
    if (b >= Btot) return;

    char* wbase = smem + wid * WLDS;
    char* myrow = wbase + lane * ROWB;
    const int jn = lane & 15;
    const int g  = lane >> 4;
    const int xb = (lane & 7) << 4;   // own-row swizzle

    // ---- load obs row (12x float4, coalesced); cvt to packed bf16 + agent idx ----
    unsigned op[24];
    float sidx = 0.0f;
    {
        const float4* g4 = reinterpret_cast<const float4*>(obs + (size_t)b * 48);
        #pragma unroll
        for (int q = 0; q < 12; ++q) {
            float4 t = g4[q];
            float va[4] = {t.x, t.y, t.z, t.w};
            #pragma unroll
            for (int e = 0; e < 4; ++e) {
                int E = 4*q + e;
                if ((E % 3) == 1 && (E / 3) > 0)   // channel-1 one-hot, value 1.0
                    sidx = fmaf(va[e], (float)(E / 3), sidx);
            }
            op[2*q]   = cvtpkbf(va[0], va[1]);
            op[2*q+1] = cvtpkbf(va[2], va[3]);
        }
    }
    const int idx = (int)(sidx + 0.5f);
    const int ai = idx >> 2;
    const int aj = idx & 3;
    // window validity bools (shared by both gathers)
    const bool rok0 = (ai >= 1), rok2 = (ai <= 2);
    const bool cok0 = (aj >= 1), cok2 = (aj <= 2);

    // ---- write own obs row to A-area (swizzled; 6 data + 2 zero slots) ----
    {
        #pragma unroll
        for (int q = 0; q < 6; ++q) {
            u32x4 v = { op[4*q], op[4*q+1], op[4*q+2], op[4*q+3] };
            *reinterpret_cast<u32x4*>(myrow + ((q * 16) ^ xb)) = v;
        }
        u32x4 z = {0u, 0u, 0u, 0u};
        *reinterpret_cast<u32x4*>(myrow + ((6 * 16) ^ xb)) = z;   // shorts 48..55
        *reinterpret_cast<u32x4*>(myrow + ((7 * 16) ^ xb)) = z;   // shorts 56..63
    }
    MEMFENCE;   // A-writes before gather reads (compiler order; HW in-order)

    // ---- sub_state gather (features 0..26); OOB -> zero-pad sentinel at short 48 ----
    // ba = 3*idx - 15 + 3*(4*dh+dw) when in-bounds (strength-reduced addressing)
    float lg0 = Lb[0], lg1 = Lb[1], lg2 = Lb[2], lg3 = Lb[3];
    {
        const int base3 = 3*idx - 15;
        #pragma unroll
        for (int dh = 0; dh < 3; ++dh)
            #pragma unroll
            for (int dw = 0; dw < 3; ++dw) {
                bool ok = (dh == 0 ? rok0 : dh == 2 ? rok2 : true) &&
                          (dw == 0 ? cok0 : dw == 2 ? cok2 : true);
                int ba = ok ? (base3 + 3*(4*dh + dw)) : 48;
                float s0 = b2f(*reinterpret_cast<const short*>(myrow + (((ba+0)*2) ^ xb)));
                float s1 = b2f(*reinterpret_cast<const short*>(myrow + (((ba+1)*2) ^ xb)));
                float s2 = b2f(*reinterpret_cast<const short*>(myrow + (((ba+2)*2) ^ xb)));
                int f = (dh*3 + dw) * 3;
                lg0 = fmaf(s0, LW[0*36+f], fmaf(s1, LW[0*36+f+1], fmaf(s2, LW[0*36+f+2], lg0)));
                lg1 = fmaf(s0, LW[1*36+f], fmaf(s1, LW[1*36+f+1], fmaf(s2, LW[1*36+f+2], lg1)));
                lg2 = fmaf(s0, LW[2*36+f], fmaf(s1, LW[2*36+f+1], fmaf(s2, LW[2*36+f+2], lg2)));
                lg3 = fmaf(s0, LW[3*36+f], fmaf(s1, LW[3*36+f+1], fmaf(s2, LW[3*36+f+2], lg3)));
            }
    }

    // ---- A-fragments: lane reads row m*16+jn, slots g and 4+g (swizzled) ----
    short8 afrag[4][2];
    #pragma unroll
    for (int m = 0; m < 4; ++m) {
        const char* rp = wbase + (m*16 + jn) * ROWB;
        const int xr = (jn & 7) << 4;
        afrag[m][0] = *reinterpret_cast<const short8*>(rp + ((16*g) ^ xr));
        afrag[m][1] = *reinterpret_cast<const short8*>(rp + ((64 + 16*g) ^ xr));
    }
    MEMFENCE;   // afrag reads before strip scatter overwrites A (WAR; in-order DS)

    // ---- 3 column-tiles with incremental f16 packing of rin/rout/p ----
    unsigned rinp[4][2], routp[4][2], pp[4][2];
    float rv[16];
    const float b0 = Phib[jn], b1 = Phib[16 + jn], b2 = Phib[32 + jn];

    tile_pass(0, wbase, jn, g, xb, afrag, PhiW, b0, rv);   // cols 0..15
    rinp[0][0] = pkrtz(rv[0], rv[6]);  routp[0][0] = pkrtz(rv[1], rv[7]);  pp[0][0] = pkrtz(rv[2], rv[8]);
    rinp[0][1] = pkrtz(rv[3], rv[9]);  routp[0][1] = pkrtz(rv[4], rv[10]); pp[0][1] = pkrtz(rv[5], rv[11]);
    float c4r = rv[12], c4o = rv[13], c4p = rv[14], c5r = rv[15];

    tile_pass(1, wbase, jn, g, xb, afrag, PhiW, b1, rv);   // cols 16..31
    {
        float c5o = rv[0], c5p = rv[1];
        rinp[1][0] = pkrtz(c4r, rv[2]); routp[1][0] = pkrtz(c4o, rv[3]); pp[1][0] = pkrtz(c4p, rv[4]);
        rinp[1][1] = pkrtz(c5r, rv[5]); routp[1][1] = pkrtz(c5o, rv[6]); pp[1][1] = pkrtz(c5p, rv[7]);
    }
    float c8r = rv[8],  c8o = rv[9],  c8p = rv[10];
    float c9r = rv[11], c9o = rv[12], c9p = rv[13];
    float c10r = rv[14], c10o = rv[15];

    tile_pass(2, wbase, jn, g, xb, afrag, PhiW, b2, rv);   // cols 32..47
    rinp[2][0] = pkrtz(c8r, c10r);     routp[2][0] = pkrtz(c8o, c10o);    pp[2][0] = pkrtz(c8p, rv[0]);
    rinp[2][1] = pkrtz(c9r, rv[1]);    routp[2][1] = pkrtz(c9o, rv[2]);   pp[2][1] = pkrtz(c9p, rv[3]);
    rinp[3][0] = pkrtz(rv[4], rv[10]); routp[3][0] = pkrtz(rv[5], rv[11]); pp[3][0] = pkrtz(rv[6], rv[12]);
    rinp[3][1] = pkrtz(rv[7], rv[13]); routp[3][1] = pkrtz(rv[8], rv[14]); pp[3][1] = pkrtz(rv[9], rv[15]);

    // ---- build per-direction a* = rin_neighbor - rout in packed f16 ----
    unsigned aL2[4][2], aR2[4][2], aU2[4][2], aD2[4][2];
    #pragma unroll
    for (int h = 0; h < 4; ++h) {
        aL2[h][0] = pksub(rinp[h][1] << 16, routp[h][0]);
        aL2[h][1] = pksub(rinp[h][0], routp[h][1]);
        aR2[h][0] = pksub(rinp[h][1], routp[h][0]);
        aR2[h][1] = pksub(rinp[h][0] >> 16, routp[h][1]);
        #pragma unroll
        for (int j = 0; j < 2; ++j) {
            aU2[h][j] = (h > 0) ? pksub(rinp[h-1][j], routp[h][j]) : pkneg(routp[0][j]);
            aD2[h][j] = (h < 3) ? pksub(rinp[h+1][j], routp[h][j]) : pkneg(routp[3][j]);
        }
    }
    // half-masked p for boundary-exact op_sel fmas (lo of pLm = 0, hi of pRm = 0)
    unsigned pLm[4], pRm[4];
    #pragma unroll
    for (int h = 0; h < 4; ++h) {
        pLm[h] = pp[h][0] & 0xFFFF0000u;
        pRm[h] = pp[h][1] & 0x0000FFFFu;
    }

    // ---- K=20 VI steps, packed f16, unrolled x2 (ping-pong) ----
    unsigned Vp[4][2], Vn[4][2];
    #pragma unroll
    for (int h = 0; h < 4; ++h) { Vp[h][0] = 0u; Vp[h][1] = 0u; }
    #pragma unroll 1
    for (int s = 0; s < 10; ++s) {
        vistep(Vp, Vn, pp, pLm, pRm, aL2, aR2, aU2, aD2);
        vistep(Vn, Vp, pp, pLm, pRm, aL2, aR2, aU2, aD2);
    }

    // ---- V to own row words 0..15 (+zero sentinel word 16), swizzled ----
    {
        #pragma unroll
        for (int h = 0; h < 4; ++h) {
            h2 a = __builtin_bit_cast(h2, Vp[h][0]);
            h2 c = __builtin_bit_cast(h2, Vp[h][1]);
            *reinterpret_cast<f32x4*>(myrow + ((h * 16) ^ xb)) =
                (f32x4){(float)a[0], (float)c[0], (float)a[1], (float)c[1]};
        }
        *reinterpret_cast<float*>(myrow + (64 ^ xb)) = 0.0f;   // word 16 sentinel
    }
    MEMFENCE;   // V writes before V gather reads (RAW; in-order DS)
    {
        const int base1 = idx - 5;
        #pragma unroll
        for (int dh = 0; dh < 3; ++dh)
            #pragma unroll
            for (int dw = 0; dw < 3; ++dw) {
                bool ok = (dh == 0 ? rok0 : dh == 2 ? rok2 : true) &&
                          (dw == 0 ? cok0 : dw == 2 ? cok2 : true);
                int ba = ok ? (base1 + 4*dh + dw) : 16;   // 16 -> zero sentinel
                float v = *reinterpret_cast<const float*>(myrow + ((ba * 4) ^ xb));
                int f = 27 + dh*3 + dw;
                lg0 = fmaf(v, LW[0*36+f], lg0);
                lg1 = fmaf(v, LW[1*36+f], lg1);
                lg2 = fmaf(v, LW[2*36+f], lg2);
                lg3 = fmaf(v, LW[3*36+f], lg3);
            }
    }

    reinterpret_cast<float4*>(out)[b] = make_float4(lg0, lg1, lg2, lg3);
}

extern "C" void kernel_launch(void* const* d_in, const int* in_sizes, int n_in,
                              void* d_out, int out_size, void* d_ws, size_t ws_size,
                              hipStream_t stream) {
    const float* obs  = (const float*)d_in[0];
    const float* PhiW = (const float*)d_in[1];
    const float* Phib = (const float*)d_in[2];
    const float* LW   = (const float*)d_in[3];
    const float* Lb   = (const float*)d_in[4];
    float* out = (float*)d_out;

    const int Btot = in_sizes[0] / 48;   // 1,000,000
    const int grid = (Btot + BT - 1) / BT;
    hipLaunchKernelGGL(vin_kernel, dim3(grid), dim3(BT), 0, stream,
                       obs, PhiW, Phib, LW, Lb, out, Btot);
}